// Round 1
// baseline (506.487 us; speedup 1.0000x reference)
//
#include <hip/hip_runtime.h>

// CrossNet (DCN cross layers), B=16384, D=4096, L=6, fp32.
//   x_{l+1} = x0 * (x_l . w_l) + b_l + x_l   per row.
// One 256-thread block per row; row lives in registers across all 6 layers.
// HBM traffic = 1x read + 1x write of the 256 MiB matrix => memory-bound,
// roofline ~85us at 6.3 TB/s.

#define BATCH 16384
#define DIM   4096
#define NLAYER 6
#define BLK 256
#define VPT 4   // float4s per thread: DIM/4/BLK = 4

__global__ __launch_bounds__(BLK) void crossnet_kernel(
    const float* __restrict__ xin,
    const float* __restrict__ w,    // [L, D]
    const float* __restrict__ bias, // [L, D]
    float* __restrict__ out)
{
    const int row  = blockIdx.x;
    const int tid  = threadIdx.x;
    const int lane = tid & 63;
    const int wave = tid >> 6;

    const float4* xrow = (const float4*)(xin + (size_t)row * DIM);

    float4 x0v[VPT], xv[VPT];
#pragma unroll
    for (int j = 0; j < VPT; ++j) {
        x0v[j] = xrow[tid + j * BLK];   // coalesced: lane-contiguous float4
        xv[j]  = x0v[j];
    }

    // 4 wave partials per reduction, parity double-buffered so a single
    // __syncthreads per layer is race-free (next write lands in other slot).
    __shared__ float red[2][4];

    for (int l = 0; l < NLAYER; ++l) {
        const float4* wl = (const float4*)(w + l * DIM);
        float p = 0.0f;
#pragma unroll
        for (int j = 0; j < VPT; ++j) {
            float4 wv = wl[tid + j * BLK];
            p = fmaf(xv[j].x, wv.x, p);
            p = fmaf(xv[j].y, wv.y, p);
            p = fmaf(xv[j].z, wv.z, p);
            p = fmaf(xv[j].w, wv.w, p);
        }
        // wave=64 shuffle reduction
#pragma unroll
        for (int off = 32; off > 0; off >>= 1)
            p += __shfl_down(p, off, 64);
        if (lane == 0) red[l & 1][wave] = p;
        __syncthreads();
        const float s = red[l & 1][0] + red[l & 1][1] + red[l & 1][2] + red[l & 1][3];

        const float4* bl = (const float4*)(bias + l * DIM);
#pragma unroll
        for (int j = 0; j < VPT; ++j) {
            float4 bv = bl[tid + j * BLK];
            xv[j].x = fmaf(x0v[j].x, s, bv.x + xv[j].x);
            xv[j].y = fmaf(x0v[j].y, s, bv.y + xv[j].y);
            xv[j].z = fmaf(x0v[j].z, s, bv.z + xv[j].z);
            xv[j].w = fmaf(x0v[j].w, s, bv.w + xv[j].w);
        }
    }

    float4* orow = (float4*)(out + (size_t)row * DIM);
#pragma unroll
    for (int j = 0; j < VPT; ++j)
        orow[tid + j * BLK] = xv[j];
}

extern "C" void kernel_launch(void* const* d_in, const int* in_sizes, int n_in,
                              void* d_out, int out_size, void* d_ws, size_t ws_size,
                              hipStream_t stream) {
    const float* xin  = (const float*)d_in[0];   // [B, D]
    const float* w    = (const float*)d_in[1];   // [L, D, 1]
    const float* bias = (const float*)d_in[2];   // [L, D]
    float* out = (float*)d_out;                  // [B, D]

    crossnet_kernel<<<BATCH, BLK, 0, stream>>>(xin, w, bias, out);
}

// Round 2
// 503.883 us; speedup vs baseline: 1.0052x; 1.0052x over previous
//
#include <hip/hip_runtime.h>

// CrossNet (DCN cross layers), B=16384, D=4096, L=6, fp32.
// Algebraic form: x_l = x0 * a_l + c_l, with
//   c_l = sum_{i<l} b_i                (row-independent vector, precomputed)
//   d_l = c_l . w_l                    (row-independent scalar, precomputed)
//   u_l = x0 . w_l                     (6 independent per-row dots)
//   a_0 = 1;  a_{l+1} = a_l*(1+u_l) + d_l
//   out  = x0 * a_L + c_L
// Main kernel: 1 row load, 6 parallel dots, ONE reduction/barrier, 1 store.
// HBM floor: ~135 MB fetch (L3 holds half of x) + 262 MB write.

#define BATCH  16384
#define DIM    4096
#define NLAYER 6
#define BLK    256
#define VPT    4      // float4 per thread: DIM/4/BLK

// ---- precompute c_L[D] and d[NLAYER] into workspace (1 block) ----
__global__ __launch_bounds__(1024) void precompute_kernel(
    const float* __restrict__ w,     // [L, D]
    const float* __restrict__ bias,  // [L, D]
    float* __restrict__ c_out,       // [D]
    float* __restrict__ d_out)       // [NLAYER]
{
    const int tid  = threadIdx.x;         // 0..1023
    const int lane = tid & 63;
    const int wave = tid >> 6;            // 0..15

    float dpart[NLAYER];
#pragma unroll
    for (int l = 0; l < NLAYER; ++l) dpart[l] = 0.0f;

#pragma unroll
    for (int k = 0; k < DIM / 1024; ++k) {
        const int j = tid + k * 1024;
        float pre = 0.0f;                 // prefix sum of bias over layers at j
#pragma unroll
        for (int l = 0; l < NLAYER; ++l) {
            dpart[l] = fmaf(pre, w[l * DIM + j], dpart[l]);
            pre += bias[l * DIM + j];
        }
        c_out[j] = pre;                   // c_L[j] = sum of all layer biases
    }

#pragma unroll
    for (int l = 0; l < NLAYER; ++l)
#pragma unroll
        for (int off = 32; off > 0; off >>= 1)
            dpart[l] += __shfl_xor(dpart[l], off, 64);

    __shared__ float red[16][NLAYER];
    if (lane == 0)
#pragma unroll
        for (int l = 0; l < NLAYER; ++l) red[wave][l] = dpart[l];
    __syncthreads();
    if (tid < NLAYER) {
        float s = 0.0f;
#pragma unroll
        for (int wv = 0; wv < 16; ++wv) s += red[wv][tid];
        d_out[tid] = s;
    }
}

// ---- main kernel: one block per row ----
__global__ __launch_bounds__(BLK) void crossnet_kernel(
    const float* __restrict__ xin,
    const float* __restrict__ w,    // [L, D]
    const float* __restrict__ c,    // [D]   (c_L)
    const float* __restrict__ d,    // [NLAYER]
    float* __restrict__ out)
{
    const int row  = blockIdx.x;
    const int tid  = threadIdx.x;
    const int lane = tid & 63;
    const int wave = tid >> 6;

    const float4* xrow = (const float4*)(xin + (size_t)row * DIM);

    float4 x0v[VPT];
#pragma unroll
    for (int j = 0; j < VPT; ++j)
        x0v[j] = xrow[tid + j * BLK];

    // 6 independent dots of x0 against each w_l
    float u[NLAYER];
#pragma unroll
    for (int l = 0; l < NLAYER; ++l) u[l] = 0.0f;
#pragma unroll
    for (int l = 0; l < NLAYER; ++l) {
        const float4* wl = (const float4*)(w + l * DIM);
#pragma unroll
        for (int j = 0; j < VPT; ++j) {
            float4 wv = wl[tid + j * BLK];
            u[l] = fmaf(x0v[j].x, wv.x, u[l]);
            u[l] = fmaf(x0v[j].y, wv.y, u[l]);
            u[l] = fmaf(x0v[j].z, wv.z, u[l]);
            u[l] = fmaf(x0v[j].w, wv.w, u[l]);
        }
    }

    // one reduction phase for all 6 values; butterfly leaves sum in all lanes
#pragma unroll
    for (int l = 0; l < NLAYER; ++l)
#pragma unroll
        for (int off = 32; off > 0; off >>= 1)
            u[l] += __shfl_xor(u[l], off, 64);

    __shared__ float red[4][NLAYER];
    if (lane == 0)
#pragma unroll
        for (int l = 0; l < NLAYER; ++l) red[wave][l] = u[l];
    __syncthreads();

    // scalar recurrence a_{l+1} = a_l*(1+s_l) + d_l
    float a = 1.0f;
#pragma unroll
    for (int l = 0; l < NLAYER; ++l) {
        const float s = red[0][l] + red[1][l] + red[2][l] + red[3][l];
        a = fmaf(a, s, a) + d[l];
    }

    const float4* cr   = (const float4*)c;
    float4*       orow = (float4*)(out + (size_t)row * DIM);
#pragma unroll
    for (int j = 0; j < VPT; ++j) {
        float4 cv = cr[tid + j * BLK];
        float4 o;
        o.x = fmaf(x0v[j].x, a, cv.x);
        o.y = fmaf(x0v[j].y, a, cv.y);
        o.z = fmaf(x0v[j].z, a, cv.z);
        o.w = fmaf(x0v[j].w, a, cv.w);
        orow[tid + j * BLK] = o;
    }
}

extern "C" void kernel_launch(void* const* d_in, const int* in_sizes, int n_in,
                              void* d_out, int out_size, void* d_ws, size_t ws_size,
                              hipStream_t stream) {
    const float* xin  = (const float*)d_in[0];   // [B, D]
    const float* w    = (const float*)d_in[1];   // [L, D, 1] == [L, D]
    const float* bias = (const float*)d_in[2];   // [L, D]
    float* out = (float*)d_out;                  // [B, D]

    float* c = (float*)d_ws;                     // [D]
    float* d = c + DIM;                          // [NLAYER]

    precompute_kernel<<<1, 1024, 0, stream>>>(w, bias, c, d);
    crossnet_kernel<<<BATCH, BLK, 0, stream>>>(xin, w, c, d, out);
}